// Round 1
// baseline (218.061 us; speedup 1.0000x reference)
//
#include <hip/hip_runtime.h>
#include <math.h>

#define RES 2048
#define NB  256

// ---------------------------------------------------------------------------
// Kernel 1: per-beam, per-axis complex tables.
//   Ux[b,i] = (re + i*im) * exp(-(x_i-x0)^2/sig^2) * exp(i*kx*x_i)
//   Vy[b,j] =               exp(-(y_j-y0)^2/sig^2) * exp(i*ky*y_j)
// so that E[i,j] = sum_b Ux[b,i] * Vy[b,j]  (complex), out = |E|^2.
// ---------------------------------------------------------------------------
__global__ void beam_tables(const float* __restrict__ theta,
                            const float* __restrict__ reA,
                            const float* __restrict__ imA,
                            const float* __restrict__ x0A,
                            const float* __restrict__ y0A,
                            const float* __restrict__ lsA,
                            const float* __restrict__ X,
                            const float* __restrict__ Y,
                            float* __restrict__ UxRe, float* __restrict__ UxIm,
                            float* __restrict__ VyRe, float* __restrict__ VyIm)
{
    const int b = blockIdx.x;
    const float th  = theta[b];
    const float re  = reA[b], im = imA[b];
    const float px  = x0A[b], py = y0A[b];
    const float sig = expf(lsA[b]) + 0.001f;
    const float is2 = 1.0f / (sig * sig);
    const float kx  = 50.0f * cosf(th);
    const float ky  = 50.0f * sinf(th);

    for (int i = threadIdx.x; i < RES; i += blockDim.x) {
        const float xv = X[(size_t)i * RES]; // X[i][0] = x_i (indexing='ij')
        const float yv = Y[i];               // Y[0][j] = y_j
        float sx, cx, sy, cy;
        sincosf(kx * xv, &sx, &cx);
        sincosf(ky * yv, &sy, &cy);
        const float dx = xv - px, dy = yv - py;
        const float ex = expf(-(dx * dx) * is2);
        const float ey = expf(-(dy * dy) * is2);
        UxRe[b * RES + i] = ex * (re * cx - im * sx);
        UxIm[b * RES + i] = ex * (re * sx + im * cx);
        VyRe[b * RES + i] = ey * cy;
        VyIm[b * RES + i] = ey * sy;
    }
}

// ---------------------------------------------------------------------------
// Kernel 2: complex GEMM  E = Ux^T * Vy  (M=N=2048, K=256), out = |E|^2.
// A layout: [k][m] (k-major, m contiguous) -> coalesced float4 staging.
// BM=128, BN=64, BK=16, 256 threads, per-thread 8x4 complex micro-tile.
// ---------------------------------------------------------------------------
#define BM 128
#define BN 64
#define BK 16
#define TM 8
#define TN 4

__global__ __launch_bounds__(256) void ewald_gemm(
    const float* __restrict__ UxRe, const float* __restrict__ UxIm,
    const float* __restrict__ VyRe, const float* __restrict__ VyIm,
    float* __restrict__ out)
{
    __shared__ float As_re[BK][BM];
    __shared__ float As_im[BK][BM];
    __shared__ float Bs_re[BK][BN];
    __shared__ float Bs_im[BK][BN];

    const int t  = threadIdx.x;
    const int tx = t & 15;   // N direction: 16 * TN(4) = 64
    const int ty = t >> 4;   // M direction: 16 * TM(8) = 128
    const int m0 = blockIdx.y * BM;
    const int n0 = blockIdx.x * BN;

    // staging maps
    const int arow = t >> 5;        // 0..7  (A row has 32 float4)
    const int acol = (t & 31) * 4;
    const int brow = t >> 4;        // 0..15 (B row has 16 float4)
    const int bcol = (t & 15) * 4;

    float accRe[TM][TN] = {};
    float accIm[TM][TN] = {};

    for (int k0 = 0; k0 < NB; k0 += BK) {
        // ---- stage A (16x128 re+im) and B (16x64 re+im) ----
        *(float4*)&As_re[arow][acol] =
            *(const float4*)&UxRe[(size_t)(k0 + arow) * RES + m0 + acol];
        *(float4*)&As_re[arow + 8][acol] =
            *(const float4*)&UxRe[(size_t)(k0 + arow + 8) * RES + m0 + acol];
        *(float4*)&As_im[arow][acol] =
            *(const float4*)&UxIm[(size_t)(k0 + arow) * RES + m0 + acol];
        *(float4*)&As_im[arow + 8][acol] =
            *(const float4*)&UxIm[(size_t)(k0 + arow + 8) * RES + m0 + acol];
        *(float4*)&Bs_re[brow][bcol] =
            *(const float4*)&VyRe[(size_t)(k0 + brow) * RES + n0 + bcol];
        *(float4*)&Bs_im[brow][bcol] =
            *(const float4*)&VyIm[(size_t)(k0 + brow) * RES + n0 + bcol];
        __syncthreads();

        // ---- compute ----
        #pragma unroll
        for (int kk = 0; kk < BK; ++kk) {
            float ar[TM], ai[TM], br[TN], bi[TN];
            *(float4*)&ar[0] = *(const float4*)&As_re[kk][ty * TM];
            *(float4*)&ar[4] = *(const float4*)&As_re[kk][ty * TM + 4];
            *(float4*)&ai[0] = *(const float4*)&As_im[kk][ty * TM];
            *(float4*)&ai[4] = *(const float4*)&As_im[kk][ty * TM + 4];
            *(float4*)&br[0] = *(const float4*)&Bs_re[kk][tx * TN];
            *(float4*)&bi[0] = *(const float4*)&Bs_im[kk][tx * TN];
            #pragma unroll
            for (int mi = 0; mi < TM; ++mi) {
                #pragma unroll
                for (int ni = 0; ni < TN; ++ni) {
                    accRe[mi][ni] += ar[mi] * br[ni] - ai[mi] * bi[ni];
                    accIm[mi][ni] += ar[mi] * bi[ni] + ai[mi] * br[ni];
                }
            }
        }
        __syncthreads();
    }

    // ---- epilogue: out = |E|^2, float4 stores ----
    #pragma unroll
    for (int mi = 0; mi < TM; ++mi) {
        float4 o;
        o.x = accRe[mi][0] * accRe[mi][0] + accIm[mi][0] * accIm[mi][0];
        o.y = accRe[mi][1] * accRe[mi][1] + accIm[mi][1] * accIm[mi][1];
        o.z = accRe[mi][2] * accRe[mi][2] + accIm[mi][2] * accIm[mi][2];
        o.w = accRe[mi][3] * accRe[mi][3] + accIm[mi][3] * accIm[mi][3];
        *(float4*)&out[(size_t)(m0 + ty * TM + mi) * RES + n0 + tx * TN] = o;
    }
}

// ---------------------------------------------------------------------------
// Fallback: direct brute force (only used if ws_size < 8 MB).
// ---------------------------------------------------------------------------
__global__ __launch_bounds__(256) void ewald_direct(
    const float* __restrict__ theta, const float* __restrict__ reA,
    const float* __restrict__ imA, const float* __restrict__ x0A,
    const float* __restrict__ y0A, const float* __restrict__ lsA,
    const float* __restrict__ X, const float* __restrict__ Y,
    float* __restrict__ out)
{
    __shared__ float kxs[NB], kys[NB], res[NB], ims[NB], pxs[NB], pys[NB], is2s[NB];
    const int t = threadIdx.x;
    if (t < NB) {
        const float th  = theta[t];
        const float sig = expf(lsA[t]) + 0.001f;
        kxs[t] = 50.0f * cosf(th);
        kys[t] = 50.0f * sinf(th);
        res[t] = reA[t];
        ims[t] = imA[t];
        pxs[t] = x0A[t];
        pys[t] = y0A[t];
        is2s[t] = 1.0f / (sig * sig);
    }
    __syncthreads();

    const size_t npix = (size_t)RES * RES;
    for (size_t idx = (size_t)blockIdx.x * blockDim.x + t; idx < npix;
         idx += (size_t)gridDim.x * blockDim.x) {
        const float xv = X[idx], yv = Y[idx];
        float er = 0.f, ei = 0.f;
        for (int b = 0; b < NB; ++b) {
            const float dx = xv - pxs[b], dy = yv - pys[b];
            const float env = __expf(-(dx * dx + dy * dy) * is2s[b]);
            const float ph = kxs[b] * xv + kys[b] * yv;
            float s, c;
            __sincosf(ph, &s, &c);
            er += env * (res[b] * c - ims[b] * s);
            ei += env * (res[b] * s + ims[b] * c);
        }
        out[idx] = er * er + ei * ei;
    }
}

// ---------------------------------------------------------------------------
extern "C" void kernel_launch(void* const* d_in, const int* in_sizes, int n_in,
                              void* d_out, int out_size, void* d_ws, size_t ws_size,
                              hipStream_t stream) {
    const float* theta = (const float*)d_in[0];
    const float* reA   = (const float*)d_in[1];
    const float* imA   = (const float*)d_in[2];
    const float* x0A   = (const float*)d_in[3];
    const float* y0A   = (const float*)d_in[4];
    const float* lsA   = (const float*)d_in[5];
    const float* X     = (const float*)d_in[6];
    const float* Y     = (const float*)d_in[7];
    float* out = (float*)d_out;

    const size_t tbl = (size_t)NB * RES;               // elements per table
    const size_t need = 4 * tbl * sizeof(float);       // 8 MB

    if (ws_size >= need) {
        float* UxRe = (float*)d_ws;
        float* UxIm = UxRe + tbl;
        float* VyRe = UxIm + tbl;
        float* VyIm = VyRe + tbl;

        beam_tables<<<NB, 256, 0, stream>>>(theta, reA, imA, x0A, y0A, lsA,
                                            X, Y, UxRe, UxIm, VyRe, VyIm);

        dim3 grid(RES / BN, RES / BM); // 32 x 16 = 512 blocks
        ewald_gemm<<<grid, 256, 0, stream>>>(UxRe, UxIm, VyRe, VyIm, out);
    } else {
        ewald_direct<<<2048, 256, 0, stream>>>(theta, reA, imA, x0A, y0A, lsA,
                                               X, Y, out);
    }
}